// Round 22
// baseline (9689.734 us; speedup 1.0000x reference)
//
#include <hip/hip_runtime.h>

#define T_STEPS 2048
#define NBATCH  64
#define ISZ     256
#define HID     512
#define BH      (NBATCH*HID)   // 32768

typedef __attribute__((ext_vector_type(8))) __bf16 bf16x8;
typedef __attribute__((ext_vector_type(4))) float  f32x4;
typedef __attribute__((ext_vector_type(2))) float  f32x2;
typedef __attribute__((ext_vector_type(4))) unsigned int u32x4;

#define MFMA __builtin_amdgcn_mfma_f32_16x16x32_bf16

__device__ __forceinline__ float sigm(float v){ return 1.0f/(1.0f+expf(-v)); }

__device__ __forceinline__ unsigned int pack2(__bf16 a, __bf16 b){
    return (unsigned int)__builtin_bit_cast(unsigned short,a)
         | ((unsigned int)__builtin_bit_cast(unsigned short,b)<<16);
}

// Round-22: R19 geometry (grid 128: 8 groups x 8 rows, 16 WGs x 32 ch) + GATE-COLOCATED
// waves. Wave wv owns channels [ch0+8wv, +8) x ALL 4 gates: col nt*16+n -> gate=2nt+(n>>3),
// ch=n&7. Eltwise becomes in-wave (f,o are shfl_xor(8) from i,g) -> G array, G-store,
// G-read and ONE BARRIER removed from the critical path. C-state in 4 regs/lane.
// Publish keeps R19's exchange layout via shfl_xor(1) channel pairing (consumer unchanged).
// HXs double-buffered so the single remaining barrier is sufficient (all cross-wave LDS
// reuse >= 1 barrier apart; desk-checked). Exchange: tag-in-data u64, fire-and-forget (R19).
// Numerics = R13/R18/R19 (0.0039): x 2-way, W_ih 2-way, W_hh 2-way, h hi-only.
__global__ void __launch_bounds__(256,1)
lstm_persist(const float* __restrict__ x, const int* __restrict__ keep,
             const float* __restrict__ Wih, const float* __restrict__ Whh,
             const float* __restrict__ bih, const float* __restrict__ bhh,
             float* __restrict__ outp, unsigned long long* __restrict__ exch)
{
    __shared__ __align__(16) char XB[2][8][1024];    // staged x (fp32), swizzled
    __shared__ __align__(16) char HXs[2][8][1024];   // staged h (bf16), swizzled, dbuf

    const int tid=threadIdx.x, wv=tid>>6, lane=tid&63, bid=blockIdx.x;
    const int g=bid&7, w=bid>>3, ch0=w*32, bbase=g*8;
    const int n=lane&15, lg=lane>>4, nr=(n<8)?n:7;

    // exch layout (R19): [group*2+slot][2048 u64]; u64 idx = row*256 + ch/2.

    // ---- persistent weights, gate-colocated cols: row = gate*HID + ch0 + wv*8 + (n&7),
    //      gate = 2*nt + (n>>3) ----
    bf16x8 whh0[2][16], whh1[2][16], wih0[2][8], wih1[2][8];
    float biasv[2];
#pragma unroll
    for (int nt=0; nt<2; ++nt){
        const int gsel = 2*nt + (n>>3);
        const int wrow = gsel*HID + ch0 + wv*8 + (n&7);
        const float* wr = Whh + (size_t)wrow*HID + lg*8;
#pragma unroll
        for (int kt=0; kt<16; ++kt){
            const float* p = wr + kt*32;
            bf16x8 b0,b1;
#pragma unroll
            for(int e=0;e<8;++e){
                float f=p[e]; __bf16 hh=(__bf16)f;
                b0[e]=hh; b1[e]=(__bf16)(f-(float)hh);
            }
            whh0[nt][kt]=b0; whh1[nt][kt]=b1;
        }
        const float* wr2 = Wih + (size_t)wrow*ISZ + lg*8;
#pragma unroll
        for (int kt=0; kt<8; ++kt){
            const float* p = wr2 + kt*32;
            bf16x8 b0,b1;
#pragma unroll
            for(int e=0;e<8;++e){
                float f=p[e]; __bf16 hh=(__bf16)f;
                b0[e]=hh; b1[e]=(__bf16)(f-(float)hh);
            }
            wih0[nt][kt]=b0; wih1[nt][kt]=b1;
        }
        biasv[nt] = bih[wrow] + bhh[wrow];
    }

    // ---- eltwise lane constants: lanes lg<2 & n<8 own (rows lg*4..+4) x channel cN ----
    const int  cN = ch0 + wv*8 + n;          // valid for n<8
    const bool ew = (lg<2) && (n<8);
    int kp = 1; if (ew) kp = keep[cN];
    float creg[4] = {0.f,0.f,0.f,0.f};       // cell state in registers

    const int c64 = tid&63, row0 = tid>>6, row1 = row0+4;

    // prologue: stage x(0)
    {
        u32x4 q0 = *(const u32x4*)((const char*)x + ((size_t)(bbase+row0)*ISZ)*4 + (size_t)c64*16);
        u32x4 q1 = *(const u32x4*)((const char*)x + ((size_t)(bbase+row1)*ISZ)*4 + (size_t)c64*16);
        *(u32x4*)&XB[0][row0][(c64^row0)*16] = q0;
        *(u32x4*)&XB[0][row1][(c64^row1)*16] = q1;
    }
    __syncthreads();

    for (int t=0; t<T_STEPS; ++t){
        const bool hasx = (t+1<T_STEPS);
        // A: issue x(t+1) stage loads
        u32x4 xq0, xq1;
        if (hasx){
            xq0 = *(const u32x4*)((const char*)x + (((size_t)(t+1)*NBATCH + bbase+row0)*ISZ)*4 + (size_t)c64*16);
            xq1 = *(const u32x4*)((const char*)x + (((size_t)(t+1)*NBATCH + bbase+row1)*ISZ)*4 + (size_t)c64*16);
        }

        // B: x-part MFMA from LDS — x 2-way split
        f32x4 a0v[2] = {{biasv[0],biasv[0],biasv[0],biasv[0]},
                        {biasv[1],biasv[1],biasv[1],biasv[1]}};
        f32x4 a1v[2] = {{0,0,0,0},{0,0,0,0}};
#pragma unroll
        for (int kt2=0; kt2<8; ++kt2){
            f32x4 xa = *(const f32x4*)&XB[t&1][nr][(((kt2*8)+lg*2+0)^nr)*16];
            f32x4 xb = *(const f32x4*)&XB[t&1][nr][(((kt2*8)+lg*2+1)^nr)*16];
            bf16x8 a0,a1;
#pragma unroll
            for(int e=0;e<4;++e){
                float f=xa[e]; __bf16 hh=(__bf16)f;
                a0[e]=hh; a1[e]=(__bf16)(f-(float)hh);
                f=xb[e]; hh=(__bf16)f;
                a0[e+4]=hh; a1[e+4]=(__bf16)(f-(float)hh);
            }
            a0v[0]=MFMA(a0,wih0[0][kt2],a0v[0],0,0,0);
            a0v[1]=MFMA(a0,wih0[1][kt2],a0v[1],0,0,0);
            a1v[0]=MFMA(a0,wih1[0][kt2],a1v[0],0,0,0);
            a1v[1]=MFMA(a0,wih1[1][kt2],a1v[1],0,0,0);
            a1v[0]=MFMA(a1,wih0[0][kt2],a1v[0],0,0,0);   // x-lo * W_hi
            a1v[1]=MFMA(a1,wih0[1][kt2],a1v[1],0,0,0);
        }

        // C: poll exchange (tag-in-data; 8 u64/thread, R19 indices)
        u32x4 hq0, hq1;
        if (t>0){
            const unsigned int need = (unsigned int)t;
            const unsigned long long* e64 = exch + (size_t)(g*2 + ((t-1)&1))*2048;
            unsigned long long q[8];
            while(1){
#pragma unroll
                for (int j=0;j<4;++j)
                    q[j]   = __hip_atomic_load(e64 + (size_t)tid*4 + j,
                                               __ATOMIC_RELAXED, __HIP_MEMORY_SCOPE_AGENT);
#pragma unroll
                for (int j=0;j<4;++j)
                    q[4+j] = __hip_atomic_load(e64 + (size_t)(tid+256)*4 + j,
                                               __ATOMIC_RELAXED, __HIP_MEMORY_SCOPE_AGENT);
                bool ok = true;
#pragma unroll
                for (int j=0;j<8;++j) ok &= ((unsigned int)(q[j]>>32) == need);
                if (ok) break;
                __builtin_amdgcn_s_sleep(1);
            }
            hq0[0]=(unsigned int)q[0]; hq0[1]=(unsigned int)q[1];
            hq0[2]=(unsigned int)q[2]; hq0[3]=(unsigned int)q[3];
            hq1[0]=(unsigned int)q[4]; hq1[1]=(unsigned int)q[5];
            hq1[2]=(unsigned int)q[6]; hq1[3]=(unsigned int)q[7];
        }

        // E: write LDS (HXs double-buffered by t&1)
        if (t>0){
            *(u32x4*)&HXs[t&1][row0][(c64^row0)*16] = hq0;
            *(u32x4*)&HXs[t&1][row1][(c64^row1)*16] = hq1;
        }
        if (hasx){
            *(u32x4*)&XB[(t+1)&1][row0][(c64^row0)*16] = xq0;
            *(u32x4*)&XB[(t+1)&1][row1][(c64^row1)*16] = xq1;
        }
        __syncthreads();   // the ONLY barrier per step

        // G: h-GEMM from LDS (h bf16 hi; W_hh 2-way split)
        if (t>0){
#pragma unroll
            for (int kt=0;kt<16;++kt){
                bf16x8 h0 = *(const bf16x8*)&HXs[t&1][nr][(((kt*4)+lg)^nr)*16];
                a0v[0]=MFMA(h0,whh0[0][kt],a0v[0],0,0,0);
                a0v[1]=MFMA(h0,whh0[1][kt],a0v[1],0,0,0);
                a1v[0]=MFMA(h0,whh1[0][kt],a1v[0],0,0,0);
                a1v[1]=MFMA(h0,whh1[1][kt],a1v[1],0,0,0);
            }
        }

        // J: IN-WAVE eltwise. Lane (lg,n) holds rows lg*4+r of cols {i,f}(nt0),{g,o}(nt1);
        //    for n<8: i=aS0, g=aS1; f,o live in lane n+8 -> shfl_xor(8).
        f32x4 aS0 = a0v[0]+a1v[0];
        f32x4 aS1 = a0v[1]+a1v[1];
        float hv[4] = {0.f,0.f,0.f,0.f};
#pragma unroll
        for (int r=0;r<4;++r){
            float fo = __shfl_xor(aS0[r], 8);   // f pre-act (for n<8 lanes)
            float oo = __shfl_xor(aS1[r], 8);   // o pre-act
            if (ew){
                creg[r] = sigm(fo)*creg[r] + sigm(aS0[r])*tanhf(aS1[r]);
                float hh = sigm(oo)*tanhf(creg[r]); if(!kp) hh=0.0f;
                hv[r] = hh;
            }
        }

        // K: publish — pair channels via shfl_xor(1); even lanes store u64 {t+1, 2xbf16}
        float hn0 = __shfl_xor(hv[0],1), hn1 = __shfl_xor(hv[1],1);
        float hn2 = __shfl_xor(hv[2],1), hn3 = __shfl_xor(hv[3],1);
        if (ew && !(n&1)){
            const float hn[4] = {hn0,hn1,hn2,hn3};
            unsigned long long* eb = exch + (size_t)(g*2+(t&1))*2048 + (cN>>1);
#pragma unroll
            for (int r=0;r<4;++r){
                unsigned long long val = ((unsigned long long)(unsigned int)(t+1) << 32)
                                       | (unsigned long long)pack2((__bf16)hv[r],(__bf16)hn[r]);
                __hip_atomic_store(eb + (size_t)(lg*4+r)*256, val,
                                   __ATOMIC_RELAXED, __HIP_MEMORY_SCOPE_AGENT);
            }
            // M: fp32 outputs (never read in-kernel)
#pragma unroll
            for (int r=0;r<4;++r){
                f32x2 ov; ov[0]=hv[r]; ov[1]=hn[r];
                *(f32x2*)(outp + (size_t)t*BH + (size_t)(bbase+lg*4+r)*HID + cN) = ov;
            }
        }
        if (t==T_STEPS-1){
            float cn0=__shfl_xor(creg[0],1), cn1=__shfl_xor(creg[1],1);
            float cn2=__shfl_xor(creg[2],1), cn3=__shfl_xor(creg[3],1);
            if (ew && !(n&1)){
                const float hn[4] = {hn0,hn1,hn2,hn3};
                const float cn[4] = {cn0,cn1,cn2,cn3};
#pragma unroll
                for (int r=0;r<4;++r){
                    f32x2 hvv; hvv[0]=hv[r];   hvv[1]=hn[r];
                    f32x2 cvv; cvv[0]=creg[r]; cvv[1]=cn[r];
                    *(f32x2*)(outp + (size_t)T_STEPS*BH + (size_t)(bbase+lg*4+r)*HID + cN)      = hvv; // h_n
                    *(f32x2*)(outp + (size_t)T_STEPS*BH + BH + (size_t)(bbase+lg*4+r)*HID + cN) = cvv; // c_n
                }
            }
        }
    }
}

extern "C" void kernel_launch(void* const* d_in, const int* in_sizes, int n_in,
                              void* d_out, int out_size, void* d_ws, size_t ws_size,
                              hipStream_t stream)
{
    // Resolve inputs by unique element count (robust to any d_in permutation).
    const void *px = nullptr, *pk = nullptr, *pwi = nullptr, *pwh = nullptr,
               *pb0 = nullptr, *pb1 = nullptr;
    for (int i = 0; i < n_in; ++i) {
        const long s = (long)in_sizes[i];
        if      (s == (long)T_STEPS * NBATCH * ISZ) px  = d_in[i];
        else if (s == HID)                          pk  = d_in[i];
        else if (s == 4L * HID * ISZ)               pwi = d_in[i];
        else if (s == 4L * HID * HID)               pwh = d_in[i];
        else if (s == 4L * HID) { if (!pb0) pb0 = d_in[i]; else pb1 = d_in[i]; }
    }
    if (!px || !pk || !pwi || !pwh || !pb0 || !pb1) {
        px = d_in[0]; pk = d_in[1]; pwi = d_in[2]; pwh = d_in[3]; pb0 = d_in[4]; pb1 = d_in[5];
    }

    lstm_persist<<<dim3(128), dim3(256), 0, stream>>>(
        (const float*)px, (const int*)pk, (const float*)pwi, (const float*)pwh,
        (const float*)pb0, (const float*)pb1, (float*)d_out,
        (unsigned long long*)d_ws);
}

// Round 23
// 6691.109 us; speedup vs baseline: 1.4482x; 1.4482x over previous
//
#include <hip/hip_runtime.h>

#define T_STEPS 2048
#define NBATCH  64
#define ISZ     256
#define HID     512
#define BH      (NBATCH*HID)   // 32768

typedef __attribute__((ext_vector_type(8))) __bf16 bf16x8;
typedef __attribute__((ext_vector_type(4))) float  f32x4;
typedef __attribute__((ext_vector_type(4))) unsigned int u32x4;

#define MFMA __builtin_amdgcn_mfma_f32_16x16x32_bf16

__device__ __forceinline__ float sigm(float v){ return 1.0f/(1.0f+expf(-v)); }

__device__ __forceinline__ unsigned int pack2(__bf16 a, __bf16 b){
    return (unsigned int)__builtin_bit_cast(unsigned short,a)
         | ((unsigned int)__builtin_bit_cast(unsigned short,b)<<16);
}

// FINAL (revert to R19, the measured optimum of this design family: 6.69 ms, absmax 0.0039).
// R20 (full-M) regressed via register spill; R21 (spill fix) still carried +185MB FETCH;
// R22 (in-wave eltwise) serialized 16-lane gate math + scattered stores (-45%). R19's
// remaining 3.27us/step = ~1.0us busy + ~2.3us coherence-point RTT + 16-WG convoy max —
// a structural floor of 2048 serial cross-chip synchronizations, not a memory/compute bound.
//
// Design: persistent kernel, grid 128 x 256 (1 WG/CU co-resident). 8 groups x 8 batch rows;
// WG owns 32 channels; wave = gate. Weights VGPR-resident as 2-way bf16 splits (hi+lo);
// x staged via double-buffered swizzled LDS; h exchanged as TAG-IN-DATA u64 {step+1, 2xbf16}
// agent-scope atomics (fire-and-forget publish; consumers poll the data itself).
// Numerics: x 2-way split on the fly, W_ih/W_hh 2-way, h hi-only -> absmax 2 bf16-ulp.
__global__ void __launch_bounds__(256,1)
lstm_persist(const float* __restrict__ x, const int* __restrict__ keep,
             const float* __restrict__ Wih, const float* __restrict__ Whh,
             const float* __restrict__ bih, const float* __restrict__ bhh,
             float* __restrict__ outp, unsigned long long* __restrict__ exch)
{
    __shared__ float G[4][8][32];                    // gate pre-activations
    __shared__ float C[8][32];                       // cell state
    __shared__ __align__(16) char XB[2][8][1024];    // staged x (fp32), swizzled
    __shared__ __align__(16) char HXs[8][1024];      // staged h (bf16), swizzled

    const int tid=threadIdx.x, wv=tid>>6, lane=tid&63, bid=blockIdx.x;
    const int g=bid&7, w=bid>>3, ch0=w*32, bbase=g*8;
    const int n=lane&15, lg=lane>>4, nr=(n<8)?n:7;

    // exch layout: [group*2+slot][2048 u64]; u64 idx = row*256 + ch/2.

    // ---- persistent weights: 2-way splits (W_hh, W_ih) ----
    bf16x8 whh0[2][16], whh1[2][16], wih0[2][8], wih1[2][8];
    float biasv[2];
#pragma unroll
    for (int nt=0; nt<2; ++nt){
        const int row = wv*HID + ch0 + nt*16 + n;
        const float* wr = Whh + (size_t)row*HID + lg*8;
#pragma unroll
        for (int kt=0; kt<16; ++kt){
            const float* p = wr + kt*32;
            bf16x8 b0,b1;
#pragma unroll
            for(int e=0;e<8;++e){
                float f=p[e]; __bf16 hh=(__bf16)f;
                b0[e]=hh; b1[e]=(__bf16)(f-(float)hh);
            }
            whh0[nt][kt]=b0; whh1[nt][kt]=b1;
        }
        const float* wr2 = Wih + (size_t)row*ISZ + lg*8;
#pragma unroll
        for (int kt=0; kt<8; ++kt){
            const float* p = wr2 + kt*32;
            bf16x8 b0,b1;
#pragma unroll
            for(int e=0;e<8;++e){
                float f=p[e]; __bf16 hh=(__bf16)f;
                b0[e]=hh; b1[e]=(__bf16)(f-(float)hh);
            }
            wih0[nt][kt]=b0; wih1[nt][kt]=b1;
        }
        biasv[nt] = bih[row] + bhh[row];
    }

    // ---- eltwise mapping: 1 channel per thread ----
    const int erow = tid>>5, ech = tid&31;
    const int kp = keep[ch0 + ech];
    C[erow][ech] = 0.0f;

    // ---- staging ids: chunks tid and tid+256 of 512 x (16B data) ----
    const int c64 = tid&63, row0 = tid>>6, row1 = row0+4;

    // prologue: stage x(0)
    {
        const char* s0 = (const char*)x + ((size_t)(bbase+row0)*ISZ)*4 + (size_t)c64*16;
        const char* s1 = (const char*)x + ((size_t)(bbase+row1)*ISZ)*4 + (size_t)c64*16;
        u32x4 q0 = *(const u32x4*)s0, q1 = *(const u32x4*)s1;
        *(u32x4*)&XB[0][row0][(c64^row0)*16] = q0;
        *(u32x4*)&XB[0][row1][(c64^row1)*16] = q1;
    }
    __syncthreads();

    for (int t=0; t<T_STEPS; ++t){
        const bool hasx = (t+1<T_STEPS);
        // A: issue x(t+1) stage loads
        u32x4 xq0, xq1;
        if (hasx){
            const char* s0 = (const char*)x + (((size_t)(t+1)*NBATCH + bbase+row0)*ISZ)*4 + (size_t)c64*16;
            const char* s1 = (const char*)x + (((size_t)(t+1)*NBATCH + bbase+row1)*ISZ)*4 + (size_t)c64*16;
            xq0 = *(const u32x4*)s0;
            xq1 = *(const u32x4*)s1;
        }

        // B: x-part MFMA from LDS — x 2-WAY SPLIT
        f32x4 a0v[2] = {{biasv[0],biasv[0],biasv[0],biasv[0]},
                        {biasv[1],biasv[1],biasv[1],biasv[1]}};
        f32x4 a1v[2] = {{0,0,0,0},{0,0,0,0}};
#pragma unroll
        for (int kt2=0; kt2<8; ++kt2){
            f32x4 xa = *(const f32x4*)&XB[t&1][nr][(((kt2*8)+lg*2+0)^nr)*16];
            f32x4 xb = *(const f32x4*)&XB[t&1][nr][(((kt2*8)+lg*2+1)^nr)*16];
            bf16x8 a0,a1;
#pragma unroll
            for(int e=0;e<4;++e){
                float f=xa[e]; __bf16 hh=(__bf16)f;
                a0[e]=hh; a1[e]=(__bf16)(f-(float)hh);
                f=xb[e]; hh=(__bf16)f;
                a0[e+4]=hh; a1[e+4]=(__bf16)(f-(float)hh);
            }
            a0v[0]=MFMA(a0,wih0[0][kt2],a0v[0],0,0,0);
            a0v[1]=MFMA(a0,wih0[1][kt2],a0v[1],0,0,0);
            a1v[0]=MFMA(a0,wih1[0][kt2],a1v[0],0,0,0);
            a1v[1]=MFMA(a0,wih1[1][kt2],a1v[1],0,0,0);
            a1v[0]=MFMA(a1,wih0[0][kt2],a1v[0],0,0,0);   // x-lo * W_hi
            a1v[1]=MFMA(a1,wih0[1][kt2],a1v[1],0,0,0);
        }

        // C/D fused: poll the exchange data directly (hi word == t means step t-1 published)
        u32x4 hq0, hq1;
        if (t>0){
            const unsigned int need = (unsigned int)t;   // producer wrote (t-1)+1
            const unsigned long long* e64 = exch + (size_t)(g*2 + ((t-1)&1))*2048;
            unsigned long long q[8];
            while(1){
#pragma unroll
                for (int j=0;j<4;++j)
                    q[j]   = __hip_atomic_load(e64 + (size_t)tid*4 + j,
                                               __ATOMIC_RELAXED, __HIP_MEMORY_SCOPE_AGENT);
#pragma unroll
                for (int j=0;j<4;++j)
                    q[4+j] = __hip_atomic_load(e64 + (size_t)(tid+256)*4 + j,
                                               __ATOMIC_RELAXED, __HIP_MEMORY_SCOPE_AGENT);
                bool ok = true;
#pragma unroll
                for (int j=0;j<8;++j) ok &= ((unsigned int)(q[j]>>32) == need);
                if (ok) break;
                __builtin_amdgcn_s_sleep(1);
            }
            hq0[0]=(unsigned int)q[0]; hq0[1]=(unsigned int)q[1];
            hq0[2]=(unsigned int)q[2]; hq0[3]=(unsigned int)q[3];
            hq1[0]=(unsigned int)q[4]; hq1[1]=(unsigned int)q[5];
            hq1[2]=(unsigned int)q[6]; hq1[3]=(unsigned int)q[7];
        }

        // E: write LDS (h data from registers; x loads compiler-waited automatically)
        if (t>0){
            *(u32x4*)&HXs[row0][(c64^row0)*16] = hq0;
            *(u32x4*)&HXs[row1][(c64^row1)*16] = hq1;
        }
        if (hasx){
            *(u32x4*)&XB[(t+1)&1][row0][(c64^row0)*16] = xq0;
            *(u32x4*)&XB[(t+1)&1][row1][(c64^row1)*16] = xq1;
        }
        __syncthreads();

        // G: h-GEMM from LDS (h bf16 hi; W_hh 2-way split)
        if (t>0){
#pragma unroll
            for (int kt=0;kt<16;++kt){
                bf16x8 h0 = *(const bf16x8*)&HXs[nr][(((kt*4)+lg)^nr)*16];
                a0v[0]=MFMA(h0,whh0[0][kt],a0v[0],0,0,0);
                a0v[1]=MFMA(h0,whh0[1][kt],a0v[1],0,0,0);
                a1v[0]=MFMA(h0,whh1[0][kt],a1v[0],0,0,0);
                a1v[1]=MFMA(h0,whh1[1][kt],a1v[1],0,0,0);
            }
        }

        // H: G store. D layout: col=lane&15, row=(lane>>4)*4+reg
        if (lane<32){
#pragma unroll
            for (int nt=0; nt<2; ++nt){
                f32x4 acc = a0v[nt]+a1v[nt];
#pragma unroll
                for(int r=0;r<4;++r) G[wv][lg*4+r][nt*16+n]=acc[r];
            }
        }
        __syncthreads();

        // J: eltwise (all waves, 1 ch/thread)
        float gi=G[0][erow][ech], gf=G[1][erow][ech], gg=G[2][erow][ech], go=G[3][erow][ech];
        float cc = sigm(gf)*C[erow][ech] + sigm(gi)*tanhf(gg);
        C[erow][ech]=cc;
        float hh = sigm(go)*tanhf(cc); if(!kp) hh=0.0f;

        // K: publish h — fire-and-forget u64 {step+1, data}; no drain, no tag, no barrier
        float hnb = __shfl_xor(hh, 1);
        if (!(tid&1)){
            unsigned long long val = ((unsigned long long)(unsigned int)(t+1) << 32)
                                   | (unsigned long long)pack2((__bf16)hh, (__bf16)hnb);
            __hip_atomic_store(exch + (size_t)(g*2+(t&1))*2048 + erow*256 + ((ch0+ech)>>1),
                               val, __ATOMIC_RELAXED, __HIP_MEMORY_SCOPE_AGENT);
        }

        // M: fp32 outputs (never read in-kernel)
        outp[(size_t)t*BH + (size_t)(bbase+erow)*HID + ch0+ech] = hh;
        if (t==T_STEPS-1){
            outp[(size_t)T_STEPS*BH + (size_t)(bbase+erow)*HID + ch0+ech]      = hh;  // h_n
            outp[(size_t)T_STEPS*BH + BH + (size_t)(bbase+erow)*HID + ch0+ech] = cc;  // c_n
        }
    }
}

extern "C" void kernel_launch(void* const* d_in, const int* in_sizes, int n_in,
                              void* d_out, int out_size, void* d_ws, size_t ws_size,
                              hipStream_t stream)
{
    // Resolve inputs by unique element count (robust to any d_in permutation).
    const void *px = nullptr, *pk = nullptr, *pwi = nullptr, *pwh = nullptr,
               *pb0 = nullptr, *pb1 = nullptr;
    for (int i = 0; i < n_in; ++i) {
        const long s = (long)in_sizes[i];
        if      (s == (long)T_STEPS * NBATCH * ISZ) px  = d_in[i];
        else if (s == HID)                          pk  = d_in[i];
        else if (s == 4L * HID * ISZ)               pwi = d_in[i];
        else if (s == 4L * HID * HID)               pwh = d_in[i];
        else if (s == 4L * HID) { if (!pb0) pb0 = d_in[i]; else pb1 = d_in[i]; }
    }
    if (!px || !pk || !pwi || !pwh || !pb0 || !pb1) {
        px = d_in[0]; pk = d_in[1]; pwi = d_in[2]; pwh = d_in[3]; pb0 = d_in[4]; pb1 = d_in[5];
    }

    lstm_persist<<<dim3(128), dim3(256), 0, stream>>>(
        (const float*)px, (const int*)pk, (const float*)pwi, (const float*)pwh,
        (const float*)pb0, (const float*)pb1, (float*)d_out,
        (unsigned long long*)d_ws);
}